// Round 21
// baseline (79.370 us; speedup 1.0000x reference)
//
#include <hip/hip_runtime.h>

#define NFREQ   257
#define NFRAMES 3751
#define NS      480000
#define HOP     128
#define WIN     512

#define NB      32
#define BN      64                  // frames per block
#define NFT     60                  // 60*64 = 3840 frames
#define STEPS   16                  // 16 k32 (one fp plane per block)
#define XWPITCH 272                 // 128 samples (256B) + 16B pad
#define XWROWS  67                  // (64-1)*128+512 = 8576 samples
#define XW_B    18224               // 67*272
#define WNYQ_B  2048                // 512 f32 weights
#define XGROUPS 1072                // 8576/8

typedef __attribute__((ext_vector_type(8))) short short8;
typedef __attribute__((ext_vector_type(4))) float f32x4;

__device__ __forceinline__ short f2bf(float f) {
    __bf16 b = (__bf16)f;
    return __builtin_bit_cast(short, b);
}
__device__ __forceinline__ float bf2f(short s) {
    unsigned int u = ((unsigned int)(unsigned short)s) << 16;
    return __builtin_bit_cast(float, u);
}

// ---- prep: bake wave-private, LANE-COALESCED A stream.
// byte ob: fpstep=ob>>14 -> fp=fpstep>>4, step=fpstep&15;
// w=(ob>>12)&3, pl=(ob>>11)&1, m=(ob>>10)&1, lane=(ob>>4)&63.
// content: basis[pl, fp*128 + w*32 + m*16 + (lane&15), step*32 + (lane>>4)*8 ..+8]
// Wave w's step image = 4KB contiguous; lane l reads byte l*16 of each 1KB chunk
// -> global_load_dwordx4 perfectly coalesced (fixes r9's 1KB-stride flaw).
__global__ __launch_bounds__(256)
void prep_basis8(const float* __restrict__ basis,
                 short* __restrict__ abL, short* __restrict__ wnyqG) {
    int g = blockIdx.x * 256 + threadIdx.x;
    if (g < 32768) {
        int ob     = g * 16;
        int fpstep = ob >> 14;               // 0..31
        int fp     = fpstep >> 4;
        int step   = fpstep & 15;
        int w      = (ob >> 12) & 3;
        int pl     = (ob >> 11) & 1;
        int m      = (ob >> 10) & 1;
        int lane   = (ob >> 4) & 63;
        int l15    = lane & 15;
        int lgrp   = lane >> 4;
        int fr     = fp * 128 + w * 32 + m * 16 + l15;   // 0..255 < 257
        int k0     = step * 32 + lgrp * 8;
        const float4* p = reinterpret_cast<const float4*>(
            basis + ((size_t)(pl * NFREQ + fr)) * WIN + k0);
        float4 a0 = p[0], a1 = p[1];
        short8 v;
        v[0]=f2bf(a0.x); v[1]=f2bf(a0.y); v[2]=f2bf(a0.z); v[3]=f2bf(a0.w);
        v[4]=f2bf(a1.x); v[5]=f2bf(a1.y); v[6]=f2bf(a1.z); v[7]=f2bf(a1.w);
        *reinterpret_cast<short8*>(reinterpret_cast<char*>(abL) + ob) = v;
    } else if (g < 32832) {                  // nyq row: real plane row 256
        int j = g - 32768;
        const float4* p = reinterpret_cast<const float4*>(basis + (size_t)256 * WIN + j * 8);
        float4 a0 = p[0], a1 = p[1];
        short8 v;
        v[0]=f2bf(a0.x); v[1]=f2bf(a0.y); v[2]=f2bf(a0.z); v[3]=f2bf(a0.w);
        v[4]=f2bf(a1.x); v[5]=f2bf(a1.y); v[6]=f2bf(a1.z); v[7]=f2bf(a1.w);
        *reinterpret_cast<short8*>(wnyqG + j * 8) = v;
    }
}

// ---- main: 128f x 64t per block (one fp), wave 32f x 64t; barrier-free loop;
// A: baked stream -> coalesced global->VGPR, register double-buffer;
// X in LDS (staged once); nyquist interleaved into the MFMA shadow ----
__global__ __launch_bounds__(256, 3)
void stft_mfma_kernel(const float* __restrict__ x,
                      const short* __restrict__ abL,
                      const short* __restrict__ wnyqG,
                      float* __restrict__ out)
{
    __shared__ __align__(16) char smem[XW_B + WNYQ_B];   // 20272 B
    char* const xw   = smem;
    float* const wny = reinterpret_cast<float*>(smem + XW_B);

    const int tid  = threadIdx.x;
    const int wave = tid >> 6;          // 0..3 : freq stack (32 rows each)
    const int lane = tid & 63;
    const int lgrp = lane >> 4;
    const int l15  = lane & 15;

    // bijective XCD chunk swizzle: 3840 = 8 * 480; fp fastest so the fp0/fp1
    // pair sharing one X window is adjacent on the same XCD (L2 hit)
    const int logical = (blockIdx.x & 7) * 480 + (blockIdx.x >> 3);
    const int fp   = logical & 1;
    const int rest = logical >> 1;
    const int ft = rest % NFT;
    const int b  = rest / NFT;
    const int t0 = ft * BN;

    // per-lane A stream base for this block's fp & wave
    const char* const aS = (const char*)abL + ((size_t)fp << 18)   // fp*16 steps*16KB
                         + (wave << 12) + lane * 16;

    // nyq weights: bf16 global -> f32 LDS (512 values, 2/thread)
    {
        short a0 = wnyqG[tid * 2], a1 = wnyqG[tid * 2 + 1];
        wny[tid * 2]     = bf2f(a0);
        wny[tid * 2 + 1] = bf2f(a1);
    }

    // ---- prologue: fp32 x window -> bf16 LDS, padded rows, reflect edges ----
    {
        const float* __restrict__ xb = x + (size_t)b * NS;
        const int sbase = t0 * 128 - 256;
        #pragma unroll
        for (int i = 0; i < 5; ++i) {
            int g = tid + i * 256;
            if (g < XGROUPS) {
                int ix = sbase + g * 8;
                short8 v;
                if (ix >= 0 && ix + 8 <= NS) {
                    const float4* p = reinterpret_cast<const float4*>(xb + ix);
                    float4 a0 = p[0], a1 = p[1];
                    v[0]=f2bf(a0.x); v[1]=f2bf(a0.y); v[2]=f2bf(a0.z); v[3]=f2bf(a0.w);
                    v[4]=f2bf(a1.x); v[5]=f2bf(a1.y); v[6]=f2bf(a1.z); v[7]=f2bf(a1.w);
                } else {
                    #pragma unroll
                    for (int q = 0; q < 8; ++q) {
                        int idx = ix + q;
                        if (idx < 0) idx = -idx;
                        if (idx >= NS + 256) { v[q] = 0; continue; }
                        if (idx >= NS) idx = 2 * NS - 2 - idx;
                        v[q] = f2bf(xb[idx]);
                    }
                }
                *reinterpret_cast<short8*>(xw + (g >> 4) * XWPITCH + (g & 15) * 16) = v;
            }
        }
    }
    __syncthreads();    // the ONLY barrier: X window visibility

    f32x4 accR[2][4], accI[2][4];
    #pragma unroll
    for (int m = 0; m < 2; ++m)
        #pragma unroll
        for (int n = 0; n < 4; ++n) {
            accR[m][n] = f32x4{0.f,0.f,0.f,0.f};
            accI[m][n] = f32x4{0.f,0.f,0.f,0.f};
        }

    // nyquist: frame fl (0..63), quarter q=lgrp; one 8-chunk per step
    const int nfl = wave * 16 + l15;
    const int nyqXoff = (nfl + lgrp) * XWPITCH;
    const float* const nyqW = wny + lgrp * 128;
    float nacc = 0.f;

    short8 R0[2], I0[2], R1[2], I1[2];

    // prologue: step 0 into set0 (coalesced 16B loads)
    R0[0] = *reinterpret_cast<const short8*>(aS);
    R0[1] = *reinterpret_cast<const short8*>(aS + 1024);
    I0[0] = *reinterpret_cast<const short8*>(aS + 2048);
    I0[1] = *reinterpret_cast<const short8*>(aS + 3072);

    // X read: frame row l15 (+nt*16), K-byte offset r8 spans 4 rows of the
    // 272B-pitch layout -> T = r8 + ((r8>>8)<<4) hops the 16B pad per row.
    #define COMPUTE(s, R, I)                                                        \
    {                                                                               \
        short8 xv[4];                                                               \
        {                                                                           \
            int r8 = (s) * 64 + lgrp * 16;                                          \
            int T  = r8 + ((r8 >> 8) << 4);                                         \
            const char* xwl = xw + l15 * XWPITCH + T;                               \
            _Pragma("unroll")                                                       \
            for (int nt = 0; nt < 4; ++nt)                                          \
                xv[nt] = *reinterpret_cast<const short8*>(xwl + nt * (16 * XWPITCH)); \
        }                                                                           \
        _Pragma("unroll")                                                           \
        for (int m = 0; m < 2; ++m)                                                 \
            _Pragma("unroll")                                                       \
            for (int nt = 0; nt < 4; ++nt) {                                        \
                accR[m][nt] = __builtin_amdgcn_mfma_f32_16x16x32_bf16(              \
                    (R)[m], xv[nt], accR[m][nt], 0, 0, 0);                          \
                accI[m][nt] = __builtin_amdgcn_mfma_f32_16x16x32_bf16(              \
                    (I)[m], xv[nt], accI[m][nt], 0, 0, 0);                          \
            }                                                                       \
        {   /* one 8-sample nyquist chunk in the MFMA shadow */                     \
            short8 nx = *reinterpret_cast<const short8*>(xw + nyqXoff + (s) * 16);  \
            const float* wrow = nyqW + (s) * 8;                                     \
            _Pragma("unroll")                                                       \
            for (int q = 0; q < 8; ++q)                                             \
                nacc = fmaf(bf2f(nx[q]), wrow[q], nacc);                            \
        }                                                                           \
    }

    #pragma unroll 1
    for (int s = 0; s < STEPS; s += 2) {
        {   // prefetch step s+1 into set1
            const char* p = aS + (size_t)(s + 1) * 16384;
            R1[0] = *reinterpret_cast<const short8*>(p);
            R1[1] = *reinterpret_cast<const short8*>(p + 1024);
            I1[0] = *reinterpret_cast<const short8*>(p + 2048);
            I1[1] = *reinterpret_cast<const short8*>(p + 3072);
        }
        COMPUTE(s, R0, I0);
        if (s + 2 < STEPS) {   // prefetch step s+2 into set0
            const char* p = aS + (size_t)(s + 2) * 16384;
            R0[0] = *reinterpret_cast<const short8*>(p);
            R0[1] = *reinterpret_cast<const short8*>(p + 1024);
            I0[0] = *reinterpret_cast<const short8*>(p + 2048);
            I0[1] = *reinterpret_cast<const short8*>(p + 3072);
        }
        COMPUTE(s + 1, R1, I1);
    }

    // ---- epilogue: magnitude + store (f = fp*128 + 0..127, all < 257) ----
    {
        float* ob = out + (size_t)b * NFREQ * NFRAMES;
        const int fb = fp * 128 + wave * 32 + lgrp * 4;
        const int tb = t0 + l15;
        #pragma unroll
        for (int m = 0; m < 2; ++m)
            #pragma unroll
            for (int nt = 0; nt < 4; ++nt) {
                int t = tb + nt * 16;
                if (t < NFRAMES) {
                    #pragma unroll
                    for (int r = 0; r < 4; ++r) {
                        int f = fb + m * 16 + r;
                        float vr = accR[m][nt][r], vi = accI[m][nt][r];
                        ob[(size_t)f * NFRAMES + t] =
                            __builtin_amdgcn_sqrtf(vr * vr + vi * vi);
                    }
                }
            }
    }

    // ---- nyquist reduce + store (fp==0 blocks only): f=256 ----
    if (fp == 0) {
        nacc += __shfl_xor(nacc, 16);
        nacc += __shfl_xor(nacc, 32);
        int t = t0 + nfl;
        if (lgrp == 0 && t < NFRAMES)
            out[((size_t)b * NFREQ + 256) * NFRAMES + t] = fabsf(nacc);
    }
}

extern "C" void kernel_launch(void* const* d_in, const int* in_sizes, int n_in,
                              void* d_out, int out_size, void* d_ws, size_t ws_size,
                              hipStream_t stream) {
    const float* x     = (const float*)d_in[0];
    const float* basis = (const float*)d_in[1];
    float* out = (float*)d_out;

    short* abL   = (short*)d_ws;                      // 2fp x 16 steps x 16KB = 512KB
    short* wnyqG = abL + 262144;                      // 512 bf16

    prep_basis8<<<dim3(129), 256, 0, stream>>>(basis, abL, wnyqG);
    stft_mfma_kernel<<<dim3(2 * NFT * NB), 256, 0, stream>>>(x, abL, wnyqG, out);  // 3840 blocks
}

// Round 22
// 77.569 us; speedup vs baseline: 1.0232x; 1.0232x over previous
//
#include <hip/hip_runtime.h>

#define NFREQ   257
#define NFRAMES 3751
#define NS      480000
#define HOP     128
#define WIN     512

#define NB      32
#define BN      128                 // frames per block
#define NFT     30                  // 30*128 = 3840 frames
#define STEPS   32                  // 2 fp * 16 k32
#define XWPITCH 272                 // 128 samples (256B) + 16B pad
#define XW_B    35632               // 131 rows * 272
#define AHALF   16384               // one A step image: [4 wave][2pl][2m][64 lane x 16B]
#define WNYQ_B  2048                // 512 f32 weights
#define XGROUPS 2096

typedef __attribute__((ext_vector_type(8))) short short8;
typedef __attribute__((ext_vector_type(4))) float f32x4;

__device__ __forceinline__ short f2bf(float f) {
    __bf16 b = (__bf16)f;
    return __builtin_bit_cast(short, b);
}
__device__ __forceinline__ float bf2f(short s) {
    unsigned int u = ((unsigned int)(unsigned short)s) << 16;
    return __builtin_bit_cast(float, u);
}
__device__ __forceinline__ void gload_lds16(const void* g, void* l) {
    __builtin_amdgcn_global_load_lds(
        (const __attribute__((address_space(1))) void*)g,
        (__attribute__((address_space(3))) void*)l, 16, 0, 0);
}

// ---- prep: bake 32-step A stream, WAVE-PRIVATE, LANE-LINEAR chunks.
// byte ob: step=ob>>14, w=(ob>>12)&3, pl=(ob>>11)&1, m=(ob>>10)&1, lane=(ob>>4)&63.
// content: basis[pl, (step>>4)*128 + w*32 + m*16 + (lane&15),
//                (step&15)*32 + (lane>>4)*8 .. +8]
// Kernel A-read: 64 lanes x contiguous 16B = 1024B contiguous ds_read_b128
// -> ZERO bank conflicts (r19's (l15*4+lgrp) perm was a 64B-stride 8-way).
__global__ __launch_bounds__(256)
void prep_basis9(const float* __restrict__ basis,
                 short* __restrict__ abL, short* __restrict__ wnyqG) {
    int g = blockIdx.x * 256 + threadIdx.x;
    if (g < 32768) {
        int ob   = g * 16;
        int step = ob >> 14;                 // 0..31
        int w    = (ob >> 12) & 3;
        int pl   = (ob >> 11) & 1;
        int m    = (ob >> 10) & 1;
        int lane = (ob >> 4) & 63;
        int l15  = lane & 15;
        int lgrp = lane >> 4;
        int fr   = (step >> 4) * 128 + w * 32 + m * 16 + l15;   // 0..255 < 257
        int k0   = (step & 15) * 32 + lgrp * 8;
        const float4* p = reinterpret_cast<const float4*>(
            basis + ((size_t)(pl * NFREQ + fr)) * WIN + k0);
        float4 a0 = p[0], a1 = p[1];
        short8 v;
        v[0]=f2bf(a0.x); v[1]=f2bf(a0.y); v[2]=f2bf(a0.z); v[3]=f2bf(a0.w);
        v[4]=f2bf(a1.x); v[5]=f2bf(a1.y); v[6]=f2bf(a1.z); v[7]=f2bf(a1.w);
        *reinterpret_cast<short8*>(reinterpret_cast<char*>(abL) + ob) = v;
    } else if (g < 32832) {                  // nyq row: real plane row 256
        int j = g - 32768;
        const float4* p = reinterpret_cast<const float4*>(basis + (size_t)256 * WIN + j * 8);
        float4 a0 = p[0], a1 = p[1];
        short8 v;
        v[0]=f2bf(a0.x); v[1]=f2bf(a0.y); v[2]=f2bf(a0.z); v[3]=f2bf(a0.w);
        v[4]=f2bf(a1.x); v[5]=f2bf(a1.y); v[6]=f2bf(a1.z); v[7]=f2bf(a1.w);
        *reinterpret_cast<short8*>(wnyqG + j * 8) = v;
    }
}

// ---- main: 128f x 128t tile, wave 32f x 128t; BARRIER-FREE K-loop
// (wave-private A staging, per-wave vmcnt only); nyq interleaved ----
__global__ __launch_bounds__(256, 2)
void stft_mfma_kernel(const float* __restrict__ x,
                      const short* __restrict__ abL,
                      const short* __restrict__ wnyqG,
                      float* __restrict__ out)
{
    __shared__ __align__(16) char smem[XW_B + 2 * AHALF + WNYQ_B];  // 70448 B
    char* const xw   = smem;
    char* const aBuf = smem + XW_B;
    float* const wny = reinterpret_cast<float*>(smem + XW_B + 2 * AHALF);

    const int tid  = threadIdx.x;
    const int wave = tid >> 6;          // 0..3 : freq stack (32 rows each)
    const int lane = tid & 63;
    const int lgrp = lane >> 4;
    const int l15  = lane & 15;

    // bijective XCD chunk swizzle: 960 = 8 * 120
    const int logical = (blockIdx.x & 7) * 120 + (blockIdx.x >> 3);
    const int ft = logical % NFT;
    const int b  = logical / NFT;
    const int t0 = ft * BN;

    const char* abLc = (const char*)abL;
    const int wBase = wave * 4096;

    // ---- prologue: issue step-0 A stage (own region) ----
    #pragma unroll
    for (int i = 0; i < 4; ++i)
        gload_lds16(abLc + wBase + i * 1024 + lane * 16,
                    aBuf + wBase + i * 1024);
    // nyq weights: bf16 global -> f32 LDS (512 values, 2/thread)
    {
        short a0 = wnyqG[tid * 2], a1 = wnyqG[tid * 2 + 1];
        wny[tid * 2]     = bf2f(a0);
        wny[tid * 2 + 1] = bf2f(a1);
    }

    // ---- prologue: fp32 x window -> bf16 LDS, padded rows, reflect edges ----
    {
        const float* __restrict__ xb = x + (size_t)b * NS;
        const int sbase = t0 * 128 - 256;
        #pragma unroll
        for (int i = 0; i < 9; ++i) {
            int g = tid + i * 256;
            if (g < XGROUPS) {
                int ix = sbase + g * 8;
                short8 v;
                if (ix >= 0 && ix + 8 <= NS) {
                    const float4* p = reinterpret_cast<const float4*>(xb + ix);
                    float4 a0 = p[0], a1 = p[1];
                    v[0]=f2bf(a0.x); v[1]=f2bf(a0.y); v[2]=f2bf(a0.z); v[3]=f2bf(a0.w);
                    v[4]=f2bf(a1.x); v[5]=f2bf(a1.y); v[6]=f2bf(a1.z); v[7]=f2bf(a1.w);
                } else {
                    #pragma unroll
                    for (int q = 0; q < 8; ++q) {
                        int idx = ix + q;
                        if (idx < 0) idx = -idx;
                        if (idx >= NS + 256) { v[q] = 0; continue; }
                        if (idx >= NS) idx = 2 * NS - 2 - idx;
                        v[q] = f2bf(xb[idx]);
                    }
                }
                *reinterpret_cast<short8*>(xw + (g >> 4) * XWPITCH + (g & 15) * 16) = v;
            }
        }
    }
    __syncthreads();    // the ONLY barrier: X window visibility

    f32x4 accR[2][8], accI[2][8];
    #pragma unroll
    for (int m = 0; m < 2; ++m)
        #pragma unroll
        for (int n = 0; n < 8; ++n) {
            accR[m][n] = f32x4{0.f,0.f,0.f,0.f};
            accI[m][n] = f32x4{0.f,0.f,0.f,0.f};
        }

    const int aPerm = lane * 16;   // lane-linear: contiguous 1024B per chunk

    // nyquist assignment: frame fl (0..127), window half h; one 8-chunk per step
    const int nfl = wave * 32 + (lane & 31);
    const int nh  = lane >> 5;
    const int nyqXbase = (nfl + 2 * nh) * XWPITCH;
    const float* const nyqW = wny + nh * 256;
    float nacc = 0.f;

    #pragma unroll 1
    for (int s = 0; s < STEPS; ++s) {
        // wait for OWN stage(s) loads only (per-wave vmcnt) — no block barrier
        asm volatile("s_waitcnt vmcnt(0)" ::: "memory");
        __builtin_amdgcn_sched_barrier(0);

        // ---- issue stage(s+1) into the other buffer (own region) ----
        if (s + 1 < STEPS) {
            const char* sb = abLc + (size_t)(s + 1) * AHALF + wBase;
            char* dst = aBuf + ((s + 1) & 1) * AHALF + wBase;
            #pragma unroll
            for (int i = 0; i < 4; ++i)
                gload_lds16(sb + i * 1024 + lane * 16, dst + i * 1024);
        }
        __builtin_amdgcn_sched_barrier(0);   // pin: stage issue precedes compute

        // ---- compute this k32 from own region of buf[s&1] ----
        const int ks32 = s & 15;
        const char* aCur = aBuf + (s & 1) * AHALF + wBase;
        short8 aRv[2], aIv[2], xv[8];
        #pragma unroll
        for (int m = 0; m < 2; ++m) {
            aRv[m] = *reinterpret_cast<const short8*>(aCur + m * 1024 + aPerm);
            aIv[m] = *reinterpret_cast<const short8*>(aCur + 2048 + m * 1024 + aPerm);
        }
        {
            int r8 = ks32 * 64 + lgrp * 16;
            int T  = r8 + ((r8 >> 8) << 4);
            const char* xwl = xw + l15 * XWPITCH + T;
            #pragma unroll
            for (int nt = 0; nt < 8; ++nt)
                xv[nt] = *reinterpret_cast<const short8*>(xwl + nt * (16 * XWPITCH));
        }
        #pragma unroll
        for (int m = 0; m < 2; ++m)
            #pragma unroll
            for (int nt = 0; nt < 8; ++nt) {
                accR[m][nt] = __builtin_amdgcn_mfma_f32_16x16x32_bf16(aRv[m], xv[nt], accR[m][nt], 0, 0, 0);
                accI[m][nt] = __builtin_amdgcn_mfma_f32_16x16x32_bf16(aIv[m], xv[nt], accI[m][nt], 0, 0, 0);
            }

        // ---- one 8-sample nyquist chunk (fills the MFMA shadow) ----
        {
            short8 nx = *reinterpret_cast<const short8*>(
                xw + nyqXbase + (s >> 4) * XWPITCH + (s & 15) * 16);
            const float* wrow = nyqW + s * 8;
            #pragma unroll
            for (int q = 0; q < 8; ++q)
                nacc = fmaf(bf2f(nx[q]), wrow[q], nacc);
        }

        // ---- per-fp epilogue (after 16 k32 steps) ----
        if ((s & 15) == 15) {
            const int fp = s >> 4;
            float* ob = out + (size_t)b * NFREQ * NFRAMES;
            const int fb = fp * 128 + wave * 32 + lgrp * 4;
            const int tb = t0 + l15;
            #pragma unroll
            for (int m = 0; m < 2; ++m)
                #pragma unroll
                for (int nt = 0; nt < 8; ++nt) {
                    int t = tb + nt * 16;
                    if (t < NFRAMES) {
                        #pragma unroll
                        for (int r = 0; r < 4; ++r) {
                            int f = fb + m * 16 + r;
                            float vr = accR[m][nt][r], vi = accI[m][nt][r];
                            ob[(size_t)f * NFRAMES + t] =
                                __builtin_amdgcn_sqrtf(vr * vr + vi * vi);
                        }
                    }
                    accR[m][nt] = f32x4{0.f,0.f,0.f,0.f};
                    accI[m][nt] = f32x4{0.f,0.f,0.f,0.f};
                }
        }
    }

    // ---- nyquist reduce + store (f=256) ----
    {
        nacc += __shfl_xor(nacc, 32);
        int t = t0 + nfl;
        if (nh == 0 && t < NFRAMES)
            out[((size_t)b * NFREQ + 256) * NFRAMES + t] = fabsf(nacc);
    }
}

extern "C" void kernel_launch(void* const* d_in, const int* in_sizes, int n_in,
                              void* d_out, int out_size, void* d_ws, size_t ws_size,
                              hipStream_t stream) {
    const float* x     = (const float*)d_in[0];
    const float* basis = (const float*)d_in[1];
    float* out = (float*)d_out;

    short* abL   = (short*)d_ws;                      // 32 steps x 16KB = 512KB
    short* wnyqG = abL + 262144;                      // 512 bf16

    prep_basis9<<<dim3(129), 256, 0, stream>>>(basis, abL, wnyqG);
    stft_mfma_kernel<<<dim3(NFT * NB), 256, 0, stream>>>(x, abL, wnyqG, out);  // 960 blocks
}

// Round 23
// 73.882 us; speedup vs baseline: 1.0743x; 1.0499x over previous
//
#include <hip/hip_runtime.h>

#define NFREQ   257
#define NFRAMES 3751
#define NS      480000
#define HOP     128
#define WIN     512

#define NB      32
#define BN      128                 // frames per block
#define NFT     30                  // 30*128 = 3840 frames
#define STEPS   32                  // 2 fp * 16 k32
#define XWPITCH 272                 // 128 samples (256B) + 16B pad
#define XW_B    35632               // 131 rows * 272
#define WNYQ_B  2048                // 512 f32 weights
#define XGROUPS 2096

typedef __attribute__((ext_vector_type(8))) short short8;
typedef __attribute__((ext_vector_type(4))) float f32x4;

__device__ __forceinline__ short f2bf(float f) {
    __bf16 b = (__bf16)f;
    return __builtin_bit_cast(short, b);
}
__device__ __forceinline__ float bf2f(short s) {
    unsigned int u = ((unsigned int)(unsigned short)s) << 16;
    return __builtin_bit_cast(float, u);
}

// ---- prep: bake 32-step A stream, WAVE-PRIVATE, LANE-LINEAR chunks.
// byte ob: step=ob>>14, w=(ob>>12)&3, pl=(ob>>11)&1, m=(ob>>10)&1, lane=(ob>>4)&63.
// content: basis[pl, (step>>4)*128 + w*32 + m*16 + (lane&15),
//                (step&15)*32 + (lane>>4)*8 .. +8]
// Direct-A read: wave w, chunk (pl,m): lane l loads byte l*16 of a contiguous
// 1KB chunk -> ONE coalesced global_load_dwordx4 (fixes r9's 1KB-stride flaw).
__global__ __launch_bounds__(256)
void prep_basis9(const float* __restrict__ basis,
                 short* __restrict__ abL, short* __restrict__ wnyqG) {
    int g = blockIdx.x * 256 + threadIdx.x;
    if (g < 32768) {
        int ob   = g * 16;
        int step = ob >> 14;                 // 0..31
        int w    = (ob >> 12) & 3;
        int pl   = (ob >> 11) & 1;
        int m    = (ob >> 10) & 1;
        int lane = (ob >> 4) & 63;
        int l15  = lane & 15;
        int lgrp = lane >> 4;
        int fr   = (step >> 4) * 128 + w * 32 + m * 16 + l15;   // 0..255 < 257
        int k0   = (step & 15) * 32 + lgrp * 8;
        const float4* p = reinterpret_cast<const float4*>(
            basis + ((size_t)(pl * NFREQ + fr)) * WIN + k0);
        float4 a0 = p[0], a1 = p[1];
        short8 v;
        v[0]=f2bf(a0.x); v[1]=f2bf(a0.y); v[2]=f2bf(a0.z); v[3]=f2bf(a0.w);
        v[4]=f2bf(a1.x); v[5]=f2bf(a1.y); v[6]=f2bf(a1.z); v[7]=f2bf(a1.w);
        *reinterpret_cast<short8*>(reinterpret_cast<char*>(abL) + ob) = v;
    } else if (g < 32832) {                  // nyq row: real plane row 256
        int j = g - 32768;
        const float4* p = reinterpret_cast<const float4*>(basis + (size_t)256 * WIN + j * 8);
        float4 a0 = p[0], a1 = p[1];
        short8 v;
        v[0]=f2bf(a0.x); v[1]=f2bf(a0.y); v[2]=f2bf(a0.z); v[3]=f2bf(a0.w);
        v[4]=f2bf(a1.x); v[5]=f2bf(a1.y); v[6]=f2bf(a1.z); v[7]=f2bf(a1.w);
        *reinterpret_cast<short8*>(wnyqG + j * 8) = v;
    }
}

// ---- main: 128f x 128t tile, wave 32f x 128t; barrier-free K-loop;
// A DIRECT global->VGPR (coalesced baked stream, register double-buffer);
// X in LDS (staged once); nyquist interleaved into the MFMA shadow ----
__global__ __launch_bounds__(256, 2)
void stft_mfma_kernel(const float* __restrict__ x,
                      const short* __restrict__ abL,
                      const short* __restrict__ wnyqG,
                      float* __restrict__ out)
{
    __shared__ __align__(16) char smem[XW_B + WNYQ_B];   // 37680 B
    char* const xw   = smem;
    float* const wny = reinterpret_cast<float*>(smem + XW_B);

    const int tid  = threadIdx.x;
    const int wave = tid >> 6;          // 0..3 : freq stack (32 rows each)
    const int lane = tid & 63;
    const int lgrp = lane >> 4;
    const int l15  = lane & 15;

    // bijective XCD chunk swizzle: 960 = 8 * 120
    const int logical = (blockIdx.x & 7) * 120 + (blockIdx.x >> 3);
    const int ft = logical % NFT;
    const int b  = logical / NFT;
    const int t0 = ft * BN;

    // per-lane A stream base for this wave
    const char* const aS = (const char*)abL + (wave << 12) + lane * 16;

    // nyq weights: bf16 global -> f32 LDS (512 values, 2/thread)
    {
        short a0 = wnyqG[tid * 2], a1 = wnyqG[tid * 2 + 1];
        wny[tid * 2]     = bf2f(a0);
        wny[tid * 2 + 1] = bf2f(a1);
    }

    // ---- prologue: fp32 x window -> bf16 LDS, padded rows, reflect edges ----
    {
        const float* __restrict__ xb = x + (size_t)b * NS;
        const int sbase = t0 * 128 - 256;
        #pragma unroll
        for (int i = 0; i < 9; ++i) {
            int g = tid + i * 256;
            if (g < XGROUPS) {
                int ix = sbase + g * 8;
                short8 v;
                if (ix >= 0 && ix + 8 <= NS) {
                    const float4* p = reinterpret_cast<const float4*>(xb + ix);
                    float4 a0 = p[0], a1 = p[1];
                    v[0]=f2bf(a0.x); v[1]=f2bf(a0.y); v[2]=f2bf(a0.z); v[3]=f2bf(a0.w);
                    v[4]=f2bf(a1.x); v[5]=f2bf(a1.y); v[6]=f2bf(a1.z); v[7]=f2bf(a1.w);
                } else {
                    #pragma unroll
                    for (int q = 0; q < 8; ++q) {
                        int idx = ix + q;
                        if (idx < 0) idx = -idx;
                        if (idx >= NS + 256) { v[q] = 0; continue; }
                        if (idx >= NS) idx = 2 * NS - 2 - idx;
                        v[q] = f2bf(xb[idx]);
                    }
                }
                *reinterpret_cast<short8*>(xw + (g >> 4) * XWPITCH + (g & 15) * 16) = v;
            }
        }
    }
    __syncthreads();    // the ONLY barrier: X window visibility

    f32x4 accR[2][8], accI[2][8];
    #pragma unroll
    for (int m = 0; m < 2; ++m)
        #pragma unroll
        for (int n = 0; n < 8; ++n) {
            accR[m][n] = f32x4{0.f,0.f,0.f,0.f};
            accI[m][n] = f32x4{0.f,0.f,0.f,0.f};
        }

    // nyquist assignment: frame fl (0..127), window half h; one 8-chunk per step
    const int nfl = wave * 32 + (lane & 31);
    const int nh  = lane >> 5;
    const int nyqXbase = (nfl + 2 * nh) * XWPITCH;
    const float* const nyqW = wny + nh * 256;
    float nacc = 0.f;

    short8 R0[2], I0[2], R1[2], I1[2];

    #define ALOAD(RS, IS, s)                                                        \
    {                                                                               \
        const char* p_ = aS + (size_t)(s) * 16384;                                  \
        (RS)[0] = *reinterpret_cast<const short8*>(p_);                             \
        (RS)[1] = *reinterpret_cast<const short8*>(p_ + 1024);                      \
        (IS)[0] = *reinterpret_cast<const short8*>(p_ + 2048);                      \
        (IS)[1] = *reinterpret_cast<const short8*>(p_ + 3072);                      \
    }

    #define COMPUTE(s, R, I)                                                        \
    {                                                                               \
        short8 xv[8];                                                               \
        {                                                                           \
            int r8 = ((s) & 15) * 64 + lgrp * 16;                                   \
            int T  = r8 + ((r8 >> 8) << 4);                                         \
            const char* xwl = xw + l15 * XWPITCH + T;                               \
            _Pragma("unroll")                                                       \
            for (int nt = 0; nt < 8; ++nt)                                          \
                xv[nt] = *reinterpret_cast<const short8*>(xwl + nt * (16 * XWPITCH)); \
        }                                                                           \
        _Pragma("unroll")                                                           \
        for (int m = 0; m < 2; ++m)                                                 \
            _Pragma("unroll")                                                       \
            for (int nt = 0; nt < 8; ++nt) {                                        \
                accR[m][nt] = __builtin_amdgcn_mfma_f32_16x16x32_bf16(              \
                    (R)[m], xv[nt], accR[m][nt], 0, 0, 0);                          \
                accI[m][nt] = __builtin_amdgcn_mfma_f32_16x16x32_bf16(              \
                    (I)[m], xv[nt], accI[m][nt], 0, 0, 0);                          \
            }                                                                       \
        {   /* one 8-sample nyquist chunk in the MFMA shadow */                     \
            short8 nx = *reinterpret_cast<const short8*>(                           \
                xw + nyqXbase + ((s) >> 4) * XWPITCH + ((s) & 15) * 16);            \
            const float* wrow = nyqW + (s) * 8;                                     \
            _Pragma("unroll")                                                       \
            for (int q = 0; q < 8; ++q)                                             \
                nacc = fmaf(bf2f(nx[q]), wrow[q], nacc);                            \
        }                                                                           \
    }

    #define EPILOGUE(fp)                                                            \
    {                                                                               \
        float* ob = out + (size_t)b * NFREQ * NFRAMES;                              \
        const int fb = (fp) * 128 + wave * 32 + lgrp * 4;                           \
        const int tb = t0 + l15;                                                    \
        _Pragma("unroll")                                                           \
        for (int m = 0; m < 2; ++m)                                                 \
            _Pragma("unroll")                                                       \
            for (int nt = 0; nt < 8; ++nt) {                                        \
                int t = tb + nt * 16;                                               \
                if (t < NFRAMES) {                                                  \
                    _Pragma("unroll")                                               \
                    for (int r = 0; r < 4; ++r) {                                   \
                        int f = fb + m * 16 + r;                                    \
                        float vr = accR[m][nt][r], vi = accI[m][nt][r];             \
                        ob[(size_t)f * NFRAMES + t] =                               \
                            __builtin_amdgcn_sqrtf(vr * vr + vi * vi);              \
                    }                                                               \
                }                                                                   \
                accR[m][nt] = f32x4{0.f,0.f,0.f,0.f};                               \
                accI[m][nt] = f32x4{0.f,0.f,0.f,0.f};                               \
            }                                                                       \
    }

    // prologue: step 0 into set0
    ALOAD(R0, I0, 0);

    #pragma unroll 1
    for (int s = 0; s < STEPS; s += 2) {
        ALOAD(R1, I1, s + 1);                 // prefetch odd step
        COMPUTE(s, R0, I0);
        if (s + 2 < STEPS) ALOAD(R0, I0, s + 2);   // prefetch next even step
        COMPUTE(s + 1, R1, I1);
        if ((s & 15) == 14) EPILOGUE(s >> 4);      // after steps 15 and 31
    }

    // ---- nyquist reduce + store (f=256) ----
    {
        nacc += __shfl_xor(nacc, 32);
        int t = t0 + nfl;
        if (nh == 0 && t < NFRAMES)
            out[((size_t)b * NFREQ + 256) * NFRAMES + t] = fabsf(nacc);
    }
}

extern "C" void kernel_launch(void* const* d_in, const int* in_sizes, int n_in,
                              void* d_out, int out_size, void* d_ws, size_t ws_size,
                              hipStream_t stream) {
    const float* x     = (const float*)d_in[0];
    const float* basis = (const float*)d_in[1];
    float* out = (float*)d_out;

    short* abL   = (short*)d_ws;                      // 32 steps x 16KB = 512KB
    short* wnyqG = abL + 262144;                      // 512 bf16

    prep_basis9<<<dim3(129), 256, 0, stream>>>(basis, abL, wnyqG);
    stft_mfma_kernel<<<dim3(NFT * NB), 256, 0, stream>>>(x, abL, wnyqG, out);  // 960 blocks
}

// Round 24
// 73.236 us; speedup vs baseline: 1.0838x; 1.0088x over previous
//
#include <hip/hip_runtime.h>

#define NFREQ   257
#define NFRAMES 3751
#define NS      480000
#define HOP     128
#define WIN     512

#define NB      32
#define BN      128                 // frames per block
#define NFT     30                  // 30*128 = 3840 frames
#define STEPS   32                  // 2 fp * 16 k32
#define XWPITCH 272                 // 128 samples (256B) + 16B pad
#define XW_B    35632               // 131 rows * 272
#define WNYQ_B  2048                // 512 f32 weights
#define XGROUPS 2096

typedef __attribute__((ext_vector_type(8))) short short8;
typedef __attribute__((ext_vector_type(4))) float f32x4;

__device__ __forceinline__ short f2bf(float f) {
    __bf16 b = (__bf16)f;
    return __builtin_bit_cast(short, b);
}
__device__ __forceinline__ float bf2f(short s) {
    unsigned int u = ((unsigned int)(unsigned short)s) << 16;
    return __builtin_bit_cast(float, u);
}

// ---- prep: bake 32-step A stream, WAVE-PRIVATE, LANE-LINEAR chunks.
// byte ob: step=ob>>14, w=(ob>>12)&3, pl=(ob>>11)&1, m=(ob>>10)&1, lane=(ob>>4)&63.
// content: basis[pl, (step>>4)*128 + w*32 + m*16 + (lane&15),
//                (step&15)*32 + (lane>>4)*8 .. +8]
// Direct-A read: lane l loads byte l*16 of a contiguous 1KB chunk ->
// ONE coalesced global_load_dwordx4 per chunk, L2-resident.
__global__ __launch_bounds__(256)
void prep_basis9(const float* __restrict__ basis,
                 short* __restrict__ abL, short* __restrict__ wnyqG) {
    int g = blockIdx.x * 256 + threadIdx.x;
    if (g < 32768) {
        int ob   = g * 16;
        int step = ob >> 14;                 // 0..31
        int w    = (ob >> 12) & 3;
        int pl   = (ob >> 11) & 1;
        int m    = (ob >> 10) & 1;
        int lane = (ob >> 4) & 63;
        int l15  = lane & 15;
        int lgrp = lane >> 4;
        int fr   = (step >> 4) * 128 + w * 32 + m * 16 + l15;   // 0..255 < 257
        int k0   = (step & 15) * 32 + lgrp * 8;
        const float4* p = reinterpret_cast<const float4*>(
            basis + ((size_t)(pl * NFREQ + fr)) * WIN + k0);
        float4 a0 = p[0], a1 = p[1];
        short8 v;
        v[0]=f2bf(a0.x); v[1]=f2bf(a0.y); v[2]=f2bf(a0.z); v[3]=f2bf(a0.w);
        v[4]=f2bf(a1.x); v[5]=f2bf(a1.y); v[6]=f2bf(a1.z); v[7]=f2bf(a1.w);
        *reinterpret_cast<short8*>(reinterpret_cast<char*>(abL) + ob) = v;
    } else if (g < 32832) {                  // nyq row: real plane row 256
        int j = g - 32768;
        const float4* p = reinterpret_cast<const float4*>(basis + (size_t)256 * WIN + j * 8);
        float4 a0 = p[0], a1 = p[1];
        short8 v;
        v[0]=f2bf(a0.x); v[1]=f2bf(a0.y); v[2]=f2bf(a0.z); v[3]=f2bf(a0.w);
        v[4]=f2bf(a1.x); v[5]=f2bf(a1.y); v[6]=f2bf(a1.z); v[7]=f2bf(a1.w);
        *reinterpret_cast<short8*>(wnyqG + j * 8) = v;
    }
}

// ---- main: 128f x 128t tile, wave 32f x 128t; barrier-free K-loop;
// A DIRECT global->VGPR (register double-buffer); X in LDS (staged once);
// nyq chunk placed in the xv lgkm window; setprio around MFMA cluster ----
__global__ __launch_bounds__(256, 2)
void stft_mfma_kernel(const float* __restrict__ x,
                      const short* __restrict__ abL,
                      const short* __restrict__ wnyqG,
                      float* __restrict__ out)
{
    __shared__ __align__(16) char smem[XW_B + WNYQ_B];   // 37680 B
    char* const xw   = smem;
    float* const wny = reinterpret_cast<float*>(smem + XW_B);

    const int tid  = threadIdx.x;
    const int wave = tid >> 6;          // 0..3 : freq stack (32 rows each)
    const int lane = tid & 63;
    const int lgrp = lane >> 4;
    const int l15  = lane & 15;

    // bijective XCD chunk swizzle: 960 = 8 * 120
    const int logical = (blockIdx.x & 7) * 120 + (blockIdx.x >> 3);
    const int ft = logical % NFT;
    const int b  = logical / NFT;
    const int t0 = ft * BN;

    // per-lane A stream base for this wave
    const char* const aS = (const char*)abL + (wave << 12) + lane * 16;

    // nyq weights: bf16 global -> f32 LDS (512 values, 2/thread)
    {
        short a0 = wnyqG[tid * 2], a1 = wnyqG[tid * 2 + 1];
        wny[tid * 2]     = bf2f(a0);
        wny[tid * 2 + 1] = bf2f(a1);
    }

    // ---- prologue: fp32 x window -> bf16 LDS, padded rows, reflect edges ----
    {
        const float* __restrict__ xb = x + (size_t)b * NS;
        const int sbase = t0 * 128 - 256;
        #pragma unroll
        for (int i = 0; i < 9; ++i) {
            int g = tid + i * 256;
            if (g < XGROUPS) {
                int ix = sbase + g * 8;
                short8 v;
                if (ix >= 0 && ix + 8 <= NS) {
                    const float4* p = reinterpret_cast<const float4*>(xb + ix);
                    float4 a0 = p[0], a1 = p[1];
                    v[0]=f2bf(a0.x); v[1]=f2bf(a0.y); v[2]=f2bf(a0.z); v[3]=f2bf(a0.w);
                    v[4]=f2bf(a1.x); v[5]=f2bf(a1.y); v[6]=f2bf(a1.z); v[7]=f2bf(a1.w);
                } else {
                    #pragma unroll
                    for (int q = 0; q < 8; ++q) {
                        int idx = ix + q;
                        if (idx < 0) idx = -idx;
                        if (idx >= NS + 256) { v[q] = 0; continue; }
                        if (idx >= NS) idx = 2 * NS - 2 - idx;
                        v[q] = f2bf(xb[idx]);
                    }
                }
                *reinterpret_cast<short8*>(xw + (g >> 4) * XWPITCH + (g & 15) * 16) = v;
            }
        }
    }
    __syncthreads();    // the ONLY barrier: X window visibility

    f32x4 accR[2][8], accI[2][8];
    #pragma unroll
    for (int m = 0; m < 2; ++m)
        #pragma unroll
        for (int n = 0; n < 8; ++n) {
            accR[m][n] = f32x4{0.f,0.f,0.f,0.f};
            accI[m][n] = f32x4{0.f,0.f,0.f,0.f};
        }

    // nyquist assignment: frame fl (0..127), window half h; one 8-chunk per step
    const int nfl = wave * 32 + (lane & 31);
    const int nh  = lane >> 5;
    const int nyqXbase = (nfl + 2 * nh) * XWPITCH;
    const float* const nyqW = wny + nh * 256;
    float nacc = 0.f;

    short8 R0[2], I0[2], R1[2], I1[2];

    #define ALOAD(RS, IS, s)                                                        \
    {                                                                               \
        const char* p_ = aS + (size_t)(s) * 16384;                                  \
        (RS)[0] = *reinterpret_cast<const short8*>(p_);                             \
        (RS)[1] = *reinterpret_cast<const short8*>(p_ + 1024);                      \
        (IS)[0] = *reinterpret_cast<const short8*>(p_ + 2048);                      \
        (IS)[1] = *reinterpret_cast<const short8*>(p_ + 3072);                      \
    }

    // xv issues first; nyq (1 lds + 16 VALU) fills the lgkm window; then the
    // MFMA cluster under raised priority (T5: barrier-free waves are role-diverse)
    #define COMPUTE(s, R, I)                                                        \
    {                                                                               \
        short8 xv[8];                                                               \
        {                                                                           \
            int r8 = ((s) & 15) * 64 + lgrp * 16;                                   \
            int T  = r8 + ((r8 >> 8) << 4);                                         \
            const char* xwl = xw + l15 * XWPITCH + T;                               \
            _Pragma("unroll")                                                       \
            for (int nt = 0; nt < 8; ++nt)                                          \
                xv[nt] = *reinterpret_cast<const short8*>(xwl + nt * (16 * XWPITCH)); \
        }                                                                           \
        {   /* nyquist chunk: executes while xv reads are in flight */              \
            short8 nx = *reinterpret_cast<const short8*>(                           \
                xw + nyqXbase + ((s) >> 4) * XWPITCH + ((s) & 15) * 16);            \
            const float* wrow = nyqW + (s) * 8;                                     \
            _Pragma("unroll")                                                       \
            for (int q = 0; q < 8; ++q)                                             \
                nacc = fmaf(bf2f(nx[q]), wrow[q], nacc);                            \
        }                                                                           \
        __builtin_amdgcn_s_setprio(1);                                              \
        _Pragma("unroll")                                                           \
        for (int m = 0; m < 2; ++m)                                                 \
            _Pragma("unroll")                                                       \
            for (int nt = 0; nt < 8; ++nt) {                                        \
                accR[m][nt] = __builtin_amdgcn_mfma_f32_16x16x32_bf16(              \
                    (R)[m], xv[nt], accR[m][nt], 0, 0, 0);                          \
                accI[m][nt] = __builtin_amdgcn_mfma_f32_16x16x32_bf16(              \
                    (I)[m], xv[nt], accI[m][nt], 0, 0, 0);                          \
            }                                                                       \
        __builtin_amdgcn_s_setprio(0);                                              \
    }

    #define EPILOGUE(fp)                                                            \
    {                                                                               \
        float* ob = out + (size_t)b * NFREQ * NFRAMES;                              \
        const int fb = (fp) * 128 + wave * 32 + lgrp * 4;                           \
        const int tb = t0 + l15;                                                    \
        _Pragma("unroll")                                                           \
        for (int m = 0; m < 2; ++m)                                                 \
            _Pragma("unroll")                                                       \
            for (int nt = 0; nt < 8; ++nt) {                                        \
                int t = tb + nt * 16;                                               \
                if (t < NFRAMES) {                                                  \
                    _Pragma("unroll")                                               \
                    for (int r = 0; r < 4; ++r) {                                   \
                        int f = fb + m * 16 + r;                                    \
                        float vr = accR[m][nt][r], vi = accI[m][nt][r];             \
                        ob[(size_t)f * NFRAMES + t] =                               \
                            __builtin_amdgcn_sqrtf(vr * vr + vi * vi);              \
                    }                                                               \
                }                                                                   \
                accR[m][nt] = f32x4{0.f,0.f,0.f,0.f};                               \
                accI[m][nt] = f32x4{0.f,0.f,0.f,0.f};                               \
            }                                                                       \
    }

    // prologue: step 0 into set0
    ALOAD(R0, I0, 0);

    #pragma unroll 1
    for (int s = 0; s < STEPS; s += 2) {
        ALOAD(R1, I1, s + 1);                 // prefetch odd step
        COMPUTE(s, R0, I0);
        if (s + 2 < STEPS) ALOAD(R0, I0, s + 2);   // prefetch next even step
        COMPUTE(s + 1, R1, I1);
        if ((s & 15) == 14) EPILOGUE(s >> 4);      // after steps 15 and 31
    }

    // ---- nyquist reduce + store (f=256) ----
    {
        nacc += __shfl_xor(nacc, 32);
        int t = t0 + nfl;
        if (nh == 0 && t < NFRAMES)
            out[((size_t)b * NFREQ + 256) * NFRAMES + t] = fabsf(nacc);
    }
}

extern "C" void kernel_launch(void* const* d_in, const int* in_sizes, int n_in,
                              void* d_out, int out_size, void* d_ws, size_t ws_size,
                              hipStream_t stream) {
    const float* x     = (const float*)d_in[0];
    const float* basis = (const float*)d_in[1];
    float* out = (float*)d_out;

    short* abL   = (short*)d_ws;                      // 32 steps x 16KB = 512KB
    short* wnyqG = abL + 262144;                      // 512 bf16

    prep_basis9<<<dim3(129), 256, 0, stream>>>(basis, abL, wnyqG);
    stft_mfma_kernel<<<dim3(NFT * NB), 256, 0, stream>>>(x, abL, wnyqG, out);  // 960 blocks
}